// Round 4
// baseline (787.775 us; speedup 1.0000x reference)
//
#include <hip/hip_runtime.h>
#include <hip/hip_bf16.h>

// Problem constants
#define BB 4
#define SS 1024
#define DD 1024
#define HH 16
#define DKH 64
#define EPS_LN 1e-6f

#define M_ROWS 4096   // B*S
#define KK 2048       // concatenated complex K (re|im)

typedef float  floatx4 __attribute__((ext_vector_type(4)));
typedef short  shortx8 __attribute__((ext_vector_type(8)));
#define MFMA16(a, b, c) __builtin_amdgcn_mfma_f32_16x16x32_bf16(a, b, c, 0, 0, 0)

// float -> bf16 (RNE) bit pattern
__device__ __forceinline__ ushort f2b(float x) {
    union { float f; unsigned u; } a; a.f = x;
    unsigned r = (a.u + 0x7fffu + ((a.u >> 16) & 1u)) >> 16;
    return (ushort)r;
}

// pack two floats into one uint of 2 bf16 (low = first)
__device__ __forceinline__ unsigned pk2(float lo, float hi) {
    return (unsigned)f2b(lo) | ((unsigned)f2b(hi) << 16);
}

// negate a bf16x8 fragment (flip sign bits)
__device__ __forceinline__ shortx8 negf(shortx8 x) {
    shortx8 r;
    #pragma unroll
    for (int i = 0; i < 8; ++i) r[i] = (short)(x[i] ^ (short)0x8000);
    return r;
}

// async global->LDS, 16 bytes per lane (lane-contiguous LDS layout required)
__device__ __forceinline__ void gl16(const void* g, void* l) {
    __builtin_amdgcn_global_load_lds(
        (const __attribute__((address_space(1))) unsigned int*)g,
        (__attribute__((address_space(3))) unsigned int*)l, 16, 0, 0);
}

// ---------------------------------------------------------------------------
// pack_x: [4096][1024] fp32 pair -> [4096][2048] bf16  (row = [re | im])
// ---------------------------------------------------------------------------
__global__ __launch_bounds__(256) void pack_x(
    const float* __restrict__ qr, const float* __restrict__ qi,
    const float* __restrict__ kr, const float* __restrict__ ki,
    const float* __restrict__ vr, const float* __restrict__ vi,
    ushort* __restrict__ Xq, ushort* __restrict__ Xk, ushort* __restrict__ Xv)
{
    const int t = blockIdx.y;
    const float* pr = t == 0 ? qr : t == 1 ? kr : vr;
    const float* pi = t == 0 ? qi : t == 1 ? ki : vi;
    ushort* X = t == 0 ? Xq : t == 1 ? Xk : Xv;
    const int idx = blockIdx.x * 256 + threadIdx.x;
    const int row = idx >> 8, c4 = (idx & 255) * 4;
    float4 a = *(const float4*)(pr + (size_t)row * 1024 + c4);
    float4 b = *(const float4*)(pi + (size_t)row * 1024 + c4);
    ushort4 ua; ua.x = f2b(a.x); ua.y = f2b(a.y); ua.z = f2b(a.z); ua.w = f2b(a.w);
    ushort4 ub; ub.x = f2b(b.x); ub.y = f2b(b.y); ub.z = f2b(b.z); ub.w = f2b(b.w);
    *(ushort4*)(X + (size_t)row * KK + c4)        = ua;
    *(ushort4*)(X + (size_t)row * KK + 1024 + c4) = ub;
}

// ---------------------------------------------------------------------------
// pack_w: [1024][1024] fp32 pair -> [2048][2048] bf16
//   row n       = [ wr[n] | -wi[n] ]   (produces Yr)
//   row 1024+n  = [ wi[n] |  wr[n] ]   (produces Yi)
// ---------------------------------------------------------------------------
__global__ __launch_bounds__(256) void pack_w(
    const float* __restrict__ ar, const float* __restrict__ ai,
    const float* __restrict__ br, const float* __restrict__ bi,
    const float* __restrict__ cr, const float* __restrict__ ci,
    const float* __restrict__ dr, const float* __restrict__ di,
    ushort* __restrict__ Bq, ushort* __restrict__ Bk,
    ushort* __restrict__ Bv, ushort* __restrict__ Bf)
{
    const int t = blockIdx.y;
    const float* wr = t == 0 ? ar : t == 1 ? br : t == 2 ? cr : dr;
    const float* wi = t == 0 ? ai : t == 1 ? bi : t == 2 ? ci : di;
    ushort* Bo = t == 0 ? Bq : t == 1 ? Bk : t == 2 ? Bv : Bf;
    const int idx = blockIdx.x * 256 + threadIdx.x;
    const int n = idx >> 8, c4 = (idx & 255) * 4;
    float4 a = *(const float4*)(wr + (size_t)n * 1024 + c4);
    float4 b = *(const float4*)(wi + (size_t)n * 1024 + c4);
    ushort4 ua; ua.x = f2b(a.x);  ua.y = f2b(a.y);  ua.z = f2b(a.z);  ua.w = f2b(a.w);
    ushort4 ub; ub.x = f2b(b.x);  ub.y = f2b(b.y);  ub.z = f2b(b.z);  ub.w = f2b(b.w);
    ushort4 un; un.x = f2b(-b.x); un.y = f2b(-b.y); un.z = f2b(-b.z); un.w = f2b(-b.w);
    *(ushort4*)(Bo + (size_t)n * KK + c4)                 = ua;
    *(ushort4*)(Bo + (size_t)n * KK + 1024 + c4)          = un;
    *(ushort4*)(Bo + (size_t)(1024 + n) * KK + c4)        = ub;
    *(ushort4*)(Bo + (size_t)(1024 + n) * KK + 1024 + c4) = ua;
}

// ---------------------------------------------------------------------------
// bf16 MFMA GEMM (m97 recipe): C[M=4096, N=2048] = A[M,2048] . B[N,2048]^T
// Epilogue modes:
//   0: QK pack  [m][h][re64|im64] bf16  (scale applied)
//   1: V packs, interleaved complex streams per dv row:
//        Vneg[(b*16+h)*64+dv][2s]   = vr,  [2s+1] = -vi
//        Vswap[(b*16+h)*64+dv][2s]  = vi,  [2s+1] =  vr
//   2: fp32 out + residual: out0=fr, out1=fi (+ resr/resi)
// ---------------------------------------------------------------------------
#define BM 128
#define BN 128
#define BK 32

__global__ __launch_bounds__(256) void bgemm_nt(
    const ushort* __restrict__ A, const ushort* __restrict__ Bm,
    void* __restrict__ out0, void* __restrict__ out1,
    const float* __restrict__ resr, const float* __restrict__ resi,
    float scale, int mode)
{
    __shared__ __align__(16) ushort As[BM * BK];
    __shared__ __align__(16) ushort Bs[BN * BK];

    const int tid = threadIdx.x;
    const int lane = tid & 63, wave = tid >> 6;
    const int l15 = lane & 15, quad = lane >> 4;
    const int m0 = blockIdx.y * BM, n0 = blockIdx.x * BN;
    const int wm = (wave & 1) * 64, wn = (wave >> 1) * 64;

    const int id0 = tid, id1 = 256 + tid;
    const ushort* ga0 = A  + (size_t)(m0 + (id0 >> 2)) * KK + (id0 & 3) * 8;
    const ushort* ga1 = A  + (size_t)(m0 + (id1 >> 2)) * KK + (id1 & 3) * 8;
    const ushort* gb0 = Bm + (size_t)(n0 + (id0 >> 2)) * KK + (id0 & 3) * 8;
    const ushort* gb1 = Bm + (size_t)(n0 + (id1 >> 2)) * KK + (id1 & 3) * 8;
    ushort* la0 = &As[id0 * 8];
    ushort* la1 = &As[id1 * 8];
    ushort* lb0 = &Bs[id0 * 8];
    ushort* lb1 = &Bs[id1 * 8];

    floatx4 acc[4][4];
    #pragma unroll
    for (int fm = 0; fm < 4; ++fm)
        #pragma unroll
        for (int fn = 0; fn < 4; ++fn)
            acc[fm][fn] = (floatx4){0.f, 0.f, 0.f, 0.f};

    for (int k0 = 0; k0 < KK; k0 += BK) {
        gl16(ga0 + k0, la0);
        gl16(ga1 + k0, la1);
        gl16(gb0 + k0, lb0);
        gl16(gb1 + k0, lb1);
        __syncthreads();

        shortx8 af[4], bf[4];
        #pragma unroll
        for (int f = 0; f < 4; ++f)
            af[f] = *(const shortx8*)&As[(wm + f * 16 + l15) * BK + quad * 8];
        #pragma unroll
        for (int f = 0; f < 4; ++f)
            bf[f] = *(const shortx8*)&Bs[(wn + f * 16 + l15) * BK + quad * 8];
        #pragma unroll
        for (int fm = 0; fm < 4; ++fm)
            #pragma unroll
            for (int fn = 0; fn < 4; ++fn)
                acc[fm][fn] = MFMA16(af[fm], bf[fn], acc[fm][fn]);
        __syncthreads();
    }

    // Epilogue. C layout: col = lane&15, row = quad*4 + reg.
    #pragma unroll
    for (int fm = 0; fm < 4; ++fm) {
        #pragma unroll
        for (int fn = 0; fn < 4; ++fn) {
            #pragma unroll
            for (int r = 0; r < 4; ++r) {
                const int m = m0 + wm + fm * 16 + quad * 4 + r;
                const int n = n0 + wn + fn * 16 + l15;
                const float v = acc[fm][fn][r] * scale;
                if (mode == 0) {
                    const int re = n < 1024 ? 0 : 64;
                    const int nn = n & 1023, h = nn >> 6, d = nn & 63;
                    ((ushort*)out0)[(size_t)m * KK + h * 128 + re + d] = f2b(v);
                } else if (mode == 1) {
                    const int nn = n & 1023, h = nn >> 6, dv = nn & 63;
                    const int bb = m >> 10, s = m & 1023;
                    const size_t row = ((size_t)((bb * HH + h) * 64 + dv)) * KK;
                    if (n < 1024) {   // real component vr
                        const ushort g = f2b(v);
                        ((ushort*)out0)[row + 2 * s]     = g;   // Vneg even = vr
                        ((ushort*)out1)[row + 2 * s + 1] = g;   // Vswap odd = vr
                    } else {          // imag component vi
                        ((ushort*)out0)[row + 2 * s + 1] = f2b(-v); // Vneg odd = -vi
                        ((ushort*)out1)[row + 2 * s]     = f2b(v);  // Vswap even = vi
                    }
                } else {
                    const int nn = n & 1023;
                    const size_t off = (size_t)m * 1024 + nn;
                    if (n < 1024) ((float*)out0)[off] = v + resr[off];
                    else          ((float*)out1)[off] = v + resi[off];
                }
            }
        }
    }
}

// ---------------------------------------------------------------------------
// Barrier-free MFMA attention + exact streamed MagMinMaxNorm.
//   o = (A - mn*P)/(mx - mn);  A = sum attn*v,  P = sum (attn/|attn|)*v
// Block = (64 q rows, h, b); each of 4 waves owns 16 q rows end-to-end:
// QK^T (2 k-subtiles) -> wave-private LDS C->A transform (no s_barrier) ->
// AV over all 64 dv with interleaved-complex V packs. Min/max in registers.
// Output: bf16 pack xo[m][2048] = [o_r (h*64+dv) | o_i].
// ---------------------------------------------------------------------------
#define APW 36   // words per LDS row: 32 complex + 4 pad

__global__ __launch_bounds__(256) void attn_mfma(
    const ushort* __restrict__ qpk, const ushort* __restrict__ kpk,
    const ushort* __restrict__ vn, const ushort* __restrict__ vs,
    ushort* __restrict__ xo)
{
    __shared__ unsigned AP[4][2][16 * APW];   // [wave][A/P][16 rows x 36 words]

    const int tid  = threadIdx.x;
    const int wave = tid >> 6, lane = tid & 63;
    const int l15  = lane & 15, quad = lane >> 4;
    const int qt = blockIdx.x, h = blockIdx.y, b = blockIdx.z;
    const size_t qrow0 = (size_t)b * SS + (size_t)qt * 64;
    const int qw = wave * 16;

    // Q fragments (A-operand), with pre-negated imag copies
    const ushort* qb = qpk + (qrow0 + qw + l15) * KK + h * 128 + quad * 8;
    shortx8 Aq0 = *(const shortx8*)(qb);
    shortx8 Aq1 = *(const shortx8*)(qb + 32);
    shortx8 Aq2 = *(const shortx8*)(qb + 64);
    shortx8 Aq3 = *(const shortx8*)(qb + 96);
    shortx8 Nq2 = negf(Aq2), Nq3 = negf(Aq3);

    const ushort* kb = kpk + ((size_t)b * SS + l15) * KK + h * 128 + quad * 8;
    const size_t vrow = ((size_t)((b * HH + h) * 64) + l15) * KK + quad * 8;
    const ushort* vnb = vn + vrow;
    const ushort* vsb = vs + vrow;

    unsigned* Asb = AP[wave][0];
    unsigned* Psb = AP[wave][1];

    floatx4 acc[4][4];   // [dvs][Ar,Ai,Pr,Pi]
    #pragma unroll
    for (int d = 0; d < 4; ++d)
        #pragma unroll
        for (int j = 0; j < 4; ++j)
            acc[d][j] = (floatx4){0.f, 0.f, 0.f, 0.f};
    float rmn[4] = {1e30f, 1e30f, 1e30f, 1e30f};
    float rmx[4] = {0.f, 0.f, 0.f, 0.f};

    // preload K fragments for iteration 0
    shortx8 Kf[2][4];
    #pragma unroll
    for (int kt = 0; kt < 2; ++kt)
        #pragma unroll
        for (int f = 0; f < 4; ++f)
            Kf[kt][f] = *(const shortx8*)(kb + (size_t)(kt * 16) * KK + f * 32);

    for (int it = 0; it < 32; ++it) {
        // ---- QK^T: this wave's 16q x 32k ----
        floatx4 cr[2], ci[2];
        #pragma unroll
        for (int kt = 0; kt < 2; ++kt) {
            floatx4 r_ = (floatx4){0.f,0.f,0.f,0.f};
            floatx4 i_ = (floatx4){0.f,0.f,0.f,0.f};
            r_ = MFMA16(Aq0, Kf[kt][0], r_); r_ = MFMA16(Aq1, Kf[kt][1], r_);
            r_ = MFMA16(Nq2, Kf[kt][2], r_); r_ = MFMA16(Nq3, Kf[kt][3], r_);
            i_ = MFMA16(Aq2, Kf[kt][0], i_); i_ = MFMA16(Aq3, Kf[kt][1], i_);
            i_ = MFMA16(Aq0, Kf[kt][2], i_); i_ = MFMA16(Aq1, Kf[kt][3], i_);
            cr[kt] = r_; ci[kt] = i_;
        }
        // prefetch next iteration's K fragments
        if (it < 31) {
            const ushort* kn = kb + (size_t)((it + 1) * 32) * KK;
            #pragma unroll
            for (int kt = 0; kt < 2; ++kt)
                #pragma unroll
                for (int f = 0; f < 4; ++f)
                    Kf[kt][f] = *(const shortx8*)(kn + (size_t)(kt * 16) * KK + f * 32);
        }

        // ---- magnitude, phase, packed LDS write (wave-private; no barrier) ----
        #pragma unroll
        for (int kt = 0; kt < 2; ++kt) {
            #pragma unroll
            for (int r = 0; r < 4; ++r) {
                const float ar = cr[kt][r], ai = ci[kt][r];
                const float s2 = fmaf(ar, ar, ai * ai);
                const float irm = s2 > 0.f ? rsqrtf(s2) : 0.f;
                const float mag = s2 * irm;
                rmn[r] = fminf(rmn[r], mag);
                rmx[r] = fmaxf(rmx[r], mag);
                const int w = (quad * 4 + r) * APW + kt * 16 + l15;
                Asb[w] = pk2(ar, ai);
                Psb[w] = pk2(ar * irm, ai * irm);
            }
        }

        // ---- AV: all 64 dv, interleaved complex K-extent 64 bf16 ----
        shortx8 Af0 = *(const shortx8*)&Asb[l15 * APW + quad * 4];
        shortx8 Af1 = *(const shortx8*)&Asb[l15 * APW + 16 + quad * 4];
        shortx8 Pf0 = *(const shortx8*)&Psb[l15 * APW + quad * 4];
        shortx8 Pf1 = *(const shortx8*)&Psb[l15 * APW + 16 + quad * 4];

        const ushort* vno = vnb + it * 64;
        const ushort* vso = vsb + it * 64;
        #pragma unroll
        for (int dvs = 0; dvs < 4; ++dvs) {
            const size_t ro = (size_t)dvs * 16 * KK;
            shortx8 Vn0 = *(const shortx8*)(vno + ro);
            shortx8 Vn1 = *(const shortx8*)(vno + ro + 32);
            shortx8 Vs0 = *(const shortx8*)(vso + ro);
            shortx8 Vs1 = *(const shortx8*)(vso + ro + 32);
            acc[dvs][0] = MFMA16(Af0, Vn0, acc[dvs][0]);
            acc[dvs][0] = MFMA16(Af1, Vn1, acc[dvs][0]);
            acc[dvs][1] = MFMA16(Af0, Vs0, acc[dvs][1]);
            acc[dvs][1] = MFMA16(Af1, Vs1, acc[dvs][1]);
            acc[dvs][2] = MFMA16(Pf0, Vn0, acc[dvs][2]);
            acc[dvs][2] = MFMA16(Pf1, Vn1, acc[dvs][2]);
            acc[dvs][3] = MFMA16(Pf0, Vs0, acc[dvs][3]);
            acc[dvs][3] = MFMA16(Pf1, Vs1, acc[dvs][3]);
        }
    }

    // ---- per-row min/max: reduce across the 16 lanes of each quad group ----
    #pragma unroll
    for (int r = 0; r < 4; ++r) {
        #pragma unroll
        for (int o = 1; o < 16; o <<= 1) {
            rmn[r] = fminf(rmn[r], __shfl_xor(rmn[r], o));
            rmx[r] = fmaxf(rmx[r], __shfl_xor(rmx[r], o));
        }
    }

    // ---- epilogue: o = (A - mn*P)/(mx - mn) -> bf16 pack ----
    #pragma unroll
    for (int r = 0; r < 4; ++r) {
        const float mn = rmn[r];
        const float d = rmx[r] - mn;
        const float invd = d > 0.f ? 1.f / d : 0.f;
        const size_t row = (qrow0 + qw + quad * 4 + r) * KK + h * 64;
        #pragma unroll
        for (int dvs = 0; dvs < 4; ++dvs) {
            const float vr_ = (acc[dvs][0][r] - mn * acc[dvs][2][r]) * invd;
            const float vi_ = (acc[dvs][1][r] - mn * acc[dvs][3][r]) * invd;
            xo[row + dvs * 16 + l15]        = f2b(vr_);
            xo[row + dvs * 16 + l15 + 1024] = f2b(vi_);
        }
    }
}

// ---------------------------------------------------------------------------
// Complex covariance-whitening layernorm, one wave per (b,s) row.
// ---------------------------------------------------------------------------
__global__ __launch_bounds__(256) void ln_kernel(
    const float* __restrict__ xr, const float* __restrict__ xi,
    const float* __restrict__ g_rr, const float* __restrict__ g_ri,
    const float* __restrict__ g_ii,
    const float* __restrict__ b_r, const float* __restrict__ b_i,
    float* __restrict__ out)
{
    const int lane = threadIdx.x & 63;
    const int wave = threadIdx.x >> 6;
    const int row  = blockIdx.x * 4 + wave;
    const float* pr = xr + (size_t)row * DD;
    const float* pi = xi + (size_t)row * DD;

    float r[16], im[16];
    float sr = 0.f, si = 0.f;
    #pragma unroll
    for (int j = 0; j < 16; ++j) {
        r[j]  = pr[lane + 64*j];
        im[j] = pi[lane + 64*j];
        sr += r[j]; si += im[j];
    }
    #pragma unroll
    for (int o = 32; o; o >>= 1) { sr += __shfl_xor(sr, o); si += __shfl_xor(si, o); }
    const float mr = sr * (1.f / DD), mi = si * (1.f / DD);

    float srr = 0.f, sii = 0.f, sri = 0.f;
    #pragma unroll
    for (int j = 0; j < 16; ++j) {
        const float a = r[j] - mr, c = im[j] - mi;
        srr = fmaf(a, a, srr); sii = fmaf(c, c, sii); sri = fmaf(a, c, sri);
    }
    #pragma unroll
    for (int o = 32; o; o >>= 1) {
        srr += __shfl_xor(srr, o); sii += __shfl_xor(sii, o); sri += __shfl_xor(sri, o);
    }
    const float Vrr = srr * (1.f / DD) + EPS_LN;
    const float Vii = sii * (1.f / DD) + EPS_LN;
    const float Vri = sri * (1.f / DD);
    const float s  = sqrtf(Vrr * Vii - Vri * Vri);
    const float t  = sqrtf(Vrr + Vii + 2.f * s);
    const float inv = 1.f / (s * t);
    const float Wrr = (Vii + s) * inv;
    const float Wii = (Vrr + s) * inv;
    const float Wri = -Vri * inv;

    #pragma unroll
    for (int j = 0; j < 16; ++j) {
        const int d = lane + 64*j;
        const float a = r[j] - mr, c = im[j] - mi;
        const float or_ = Wrr * a + Wri * c;
        const float oi_ = Wri * a + Wii * c;
        out[(size_t)row * DD + d] = g_rr[d]*or_ + g_ri[d]*oi_ + b_r[d];
        out[(size_t)(M_ROWS) * DD + (size_t)row * DD + d] = g_ri[d]*or_ + g_ii[d]*oi_ + b_i[d];
    }
}

// ---------------------------------------------------------------------------
extern "C" void kernel_launch(void* const* d_in, const int* in_sizes, int n_in,
                              void* d_out, int out_size, void* d_ws, size_t ws_size,
                              hipStream_t stream) {
    const float* q_r  = (const float*)d_in[0];
    const float* q_i  = (const float*)d_in[1];
    const float* k_r  = (const float*)d_in[2];
    const float* k_i  = (const float*)d_in[3];
    const float* v_r  = (const float*)d_in[4];
    const float* v_i  = (const float*)d_in[5];
    const float* wq_r = (const float*)d_in[6];
    const float* wq_i = (const float*)d_in[7];
    const float* wk_r = (const float*)d_in[8];
    const float* wk_i = (const float*)d_in[9];
    const float* wv_r = (const float*)d_in[10];
    const float* wv_i = (const float*)d_in[11];
    const float* fc_r = (const float*)d_in[12];
    const float* fc_i = (const float*)d_in[13];
    const float* g_rr = (const float*)d_in[14];
    const float* g_ri = (const float*)d_in[15];
    const float* g_ii = (const float*)d_in[16];
    const float* b_r  = (const float*)d_in[17];
    const float* b_i  = (const float*)d_in[18];
    float* out = (float*)d_out;

    // Workspace: 7 units of 16 MiB = 112 MiB.
    float* ws = (float*)d_ws;
    const size_t NE = (size_t)M_ROWS * 1024;        // 4M floats = 16 MiB
    ushort* Xq   = (ushort*)(ws + 0 * NE);          // u0; later Vneg
    ushort* Xk   = (ushort*)(ws + 1 * NE);          // u1; later Vswap
    ushort* Xv   = (ushort*)(ws + 2 * NE);          // u2; later xo
    ushort* qpk  = (ushort*)(ws + 3 * NE);          // u3; later fr
    ushort* kpk  = (ushort*)(ws + 4 * NE);          // u4; later fi
    ushort* Bq   = (ushort*)(ws + 5 * NE);          // u5 lo
    ushort* Bk   = Bq + (size_t)KK * KK;            // u5 hi
    ushort* Bv   = (ushort*)(ws + 6 * NE);          // u6 lo
    ushort* Bf   = Bv + (size_t)KK * KK;            // u6 hi
    ushort* Vneg = (ushort*)(ws + 0 * NE);          // aliases dead Xq
    ushort* Vswp = (ushort*)(ws + 1 * NE);          // aliases dead Xk
    ushort* xo   = (ushort*)(ws + 2 * NE);          // aliases dead Xv
    float*  fr   = ws + 3 * NE;                     // aliases dead qpk
    float*  fi   = ws + 4 * NE;                     // aliases dead kpk

    // bf16 operand packing
    pack_x<<<dim3(4096, 3), 256, 0, stream>>>(q_r, q_i, k_r, k_i, v_r, v_i, Xq, Xk, Xv);
    pack_w<<<dim3(1024, 4), 256, 0, stream>>>(wq_r, wq_i, wk_r, wk_i, wv_r, wv_i,
                                              fc_r, fc_i, Bq, Bk, Bv, Bf);

    const dim3 gg(KK / BN, M_ROWS / BM);  // (16, 32) = 512 blocks

    // projections (q gets 1/sqrt(DK) folded in); order matters for aliasing:
    bgemm_nt<<<gg, 256, 0, stream>>>(Xq, Bq, qpk, nullptr, nullptr, nullptr, 0.125f, 0);
    bgemm_nt<<<gg, 256, 0, stream>>>(Xk, Bk, kpk, nullptr, nullptr, nullptr, 1.0f,  0);
    bgemm_nt<<<gg, 256, 0, stream>>>(Xv, Bv, Vneg, Vswp,  nullptr, nullptr, 1.0f,  1);

    // barrier-free MFMA attention + MagMinMaxNorm -> bf16 [4096][2048] pack
    attn_mfma<<<dim3(SS / 64, HH, BB), 256, 0, stream>>>(qpk, kpk, Vneg, Vswp, xo);

    // output projection + residual (bf16 MFMA, fp32 out)
    bgemm_nt<<<gg, 256, 0, stream>>>(xo, Bf, fr, fi, q_r, q_i, 1.0f, 2);

    // complex layernorm -> d_out [2,B,S,D]
    ln_kernel<<<M_ROWS / 4, 256, 0, stream>>>(fr, fi, g_rr, g_ri, g_ii, b_r, b_i, out);
}

// Round 5
// 650.352 us; speedup vs baseline: 1.2113x; 1.2113x over previous
//
#include <hip/hip_runtime.h>
#include <hip/hip_bf16.h>

// Problem constants
#define BB 4
#define SS 1024
#define DD 1024
#define HH 16
#define DKH 64
#define EPS_LN 1e-6f

#define M_ROWS 4096   // B*S
#define KK 2048       // concatenated complex K (re|im)

typedef float  floatx4 __attribute__((ext_vector_type(4)));
typedef short  shortx8 __attribute__((ext_vector_type(8)));
#define MFMA16(a, b, c) __builtin_amdgcn_mfma_f32_16x16x32_bf16(a, b, c, 0, 0, 0)

// float -> bf16 (RNE) bit pattern
__device__ __forceinline__ ushort f2b(float x) {
    union { float f; unsigned u; } a; a.f = x;
    unsigned r = (a.u + 0x7fffu + ((a.u >> 16) & 1u)) >> 16;
    return (ushort)r;
}

// pack two floats into one uint of 2 bf16 (low = first)
__device__ __forceinline__ unsigned pk2(float lo, float hi) {
    return (unsigned)f2b(lo) | ((unsigned)f2b(hi) << 16);
}

// negate a bf16x8 fragment (flip sign bits)
__device__ __forceinline__ shortx8 negf(shortx8 x) {
    shortx8 r;
    #pragma unroll
    for (int i = 0; i < 8; ++i) r[i] = (short)(x[i] ^ (short)0x8000);
    return r;
}

// async global->LDS, 16 bytes per lane (lane-contiguous LDS layout required)
__device__ __forceinline__ void gl16(const void* g, void* l) {
    __builtin_amdgcn_global_load_lds(
        (const __attribute__((address_space(1))) unsigned int*)g,
        (__attribute__((address_space(3))) unsigned int*)l, 16, 0, 0);
}

// ---------------------------------------------------------------------------
// pack_x: [4096][1024] fp32 pair -> [4096][2048] bf16  (row = [re | im])
// ---------------------------------------------------------------------------
__global__ __launch_bounds__(256) void pack_x(
    const float* __restrict__ qr, const float* __restrict__ qi,
    const float* __restrict__ kr, const float* __restrict__ ki,
    const float* __restrict__ vr, const float* __restrict__ vi,
    ushort* __restrict__ Xq, ushort* __restrict__ Xk, ushort* __restrict__ Xv)
{
    const int t = blockIdx.y;
    const float* pr = t == 0 ? qr : t == 1 ? kr : vr;
    const float* pi = t == 0 ? qi : t == 1 ? ki : vi;
    ushort* X = t == 0 ? Xq : t == 1 ? Xk : Xv;
    const int idx = blockIdx.x * 256 + threadIdx.x;
    const int row = idx >> 8, c4 = (idx & 255) * 4;
    float4 a = *(const float4*)(pr + (size_t)row * 1024 + c4);
    float4 b = *(const float4*)(pi + (size_t)row * 1024 + c4);
    ushort4 ua; ua.x = f2b(a.x); ua.y = f2b(a.y); ua.z = f2b(a.z); ua.w = f2b(a.w);
    ushort4 ub; ub.x = f2b(b.x); ub.y = f2b(b.y); ub.z = f2b(b.z); ub.w = f2b(b.w);
    *(ushort4*)(X + (size_t)row * KK + c4)        = ua;
    *(ushort4*)(X + (size_t)row * KK + 1024 + c4) = ub;
}

// ---------------------------------------------------------------------------
// pack_w: [1024][1024] fp32 pair -> [2048][2048] bf16
//   row n       = [ wr[n] | -wi[n] ]   (produces Yr)
//   row 1024+n  = [ wi[n] |  wr[n] ]   (produces Yi)
// ---------------------------------------------------------------------------
__global__ __launch_bounds__(256) void pack_w(
    const float* __restrict__ ar, const float* __restrict__ ai,
    const float* __restrict__ br, const float* __restrict__ bi,
    const float* __restrict__ cr, const float* __restrict__ ci,
    const float* __restrict__ dr, const float* __restrict__ di,
    ushort* __restrict__ Bq, ushort* __restrict__ Bk,
    ushort* __restrict__ Bv, ushort* __restrict__ Bf)
{
    const int t = blockIdx.y;
    const float* wr = t == 0 ? ar : t == 1 ? br : t == 2 ? cr : dr;
    const float* wi = t == 0 ? ai : t == 1 ? bi : t == 2 ? ci : di;
    ushort* Bo = t == 0 ? Bq : t == 1 ? Bk : t == 2 ? Bv : Bf;
    const int idx = blockIdx.x * 256 + threadIdx.x;
    const int n = idx >> 8, c4 = (idx & 255) * 4;
    float4 a = *(const float4*)(wr + (size_t)n * 1024 + c4);
    float4 b = *(const float4*)(wi + (size_t)n * 1024 + c4);
    ushort4 ua; ua.x = f2b(a.x);  ua.y = f2b(a.y);  ua.z = f2b(a.z);  ua.w = f2b(a.w);
    ushort4 ub; ub.x = f2b(b.x);  ub.y = f2b(b.y);  ub.z = f2b(b.z);  ub.w = f2b(b.w);
    ushort4 un; un.x = f2b(-b.x); un.y = f2b(-b.y); un.z = f2b(-b.z); un.w = f2b(-b.w);
    *(ushort4*)(Bo + (size_t)n * KK + c4)                 = ua;
    *(ushort4*)(Bo + (size_t)n * KK + 1024 + c4)          = un;
    *(ushort4*)(Bo + (size_t)(1024 + n) * KK + c4)        = ub;
    *(ushort4*)(Bo + (size_t)(1024 + n) * KK + 1024 + c4) = ua;
}

// ---------------------------------------------------------------------------
// bf16 MFMA GEMM body (m97 recipe): C[M, N=2048] = A[M,2048] . B[N,2048]^T
// Epilogue modes:
//   0: QK pack  [m][h][re64|im64] bf16  (scale applied)
//   1: V packs, interleaved complex streams per dv row:
//        Vneg[(b*16+h)*64+dv][2s]   = vr,  [2s+1] = -vi
//        Vswap[(b*16+h)*64+dv][2s]  = vi,  [2s+1] =  vr
//   2: fp32 out + residual: out0=fr, out1=fi (+ resr/resi)
// ---------------------------------------------------------------------------
#define BM 128
#define BN 128
#define BK 32

__device__ __forceinline__ void bgemm_body(
    const ushort* __restrict__ A, const ushort* __restrict__ Bm,
    void* __restrict__ out0, void* __restrict__ out1,
    const float* __restrict__ resr, const float* __restrict__ resi,
    float scale, int mode, int bx, int by)
{
    __shared__ __align__(16) ushort As[BM * BK];
    __shared__ __align__(16) ushort Bs[BN * BK];

    const int tid = threadIdx.x;
    const int lane = tid & 63, wave = tid >> 6;
    const int l15 = lane & 15, quad = lane >> 4;
    const int m0 = by * BM, n0 = bx * BN;
    const int wm = (wave & 1) * 64, wn = (wave >> 1) * 64;

    const int id0 = tid, id1 = 256 + tid;
    const ushort* ga0 = A  + (size_t)(m0 + (id0 >> 2)) * KK + (id0 & 3) * 8;
    const ushort* ga1 = A  + (size_t)(m0 + (id1 >> 2)) * KK + (id1 & 3) * 8;
    const ushort* gb0 = Bm + (size_t)(n0 + (id0 >> 2)) * KK + (id0 & 3) * 8;
    const ushort* gb1 = Bm + (size_t)(n0 + (id1 >> 2)) * KK + (id1 & 3) * 8;
    ushort* la0 = &As[id0 * 8];
    ushort* la1 = &As[id1 * 8];
    ushort* lb0 = &Bs[id0 * 8];
    ushort* lb1 = &Bs[id1 * 8];

    floatx4 acc[4][4];
    #pragma unroll
    for (int fm = 0; fm < 4; ++fm)
        #pragma unroll
        for (int fn = 0; fn < 4; ++fn)
            acc[fm][fn] = (floatx4){0.f, 0.f, 0.f, 0.f};

    for (int k0 = 0; k0 < KK; k0 += BK) {
        gl16(ga0 + k0, la0);
        gl16(ga1 + k0, la1);
        gl16(gb0 + k0, lb0);
        gl16(gb1 + k0, lb1);
        __syncthreads();

        shortx8 af[4], bf[4];
        #pragma unroll
        for (int f = 0; f < 4; ++f)
            af[f] = *(const shortx8*)&As[(wm + f * 16 + l15) * BK + quad * 8];
        #pragma unroll
        for (int f = 0; f < 4; ++f)
            bf[f] = *(const shortx8*)&Bs[(wn + f * 16 + l15) * BK + quad * 8];
        #pragma unroll
        for (int fm = 0; fm < 4; ++fm)
            #pragma unroll
            for (int fn = 0; fn < 4; ++fn)
                acc[fm][fn] = MFMA16(af[fm], bf[fn], acc[fm][fn]);
        __syncthreads();
    }

    // Epilogue. C layout: col = lane&15, row = quad*4 + reg.
    #pragma unroll
    for (int fm = 0; fm < 4; ++fm) {
        #pragma unroll
        for (int fn = 0; fn < 4; ++fn) {
            #pragma unroll
            for (int r = 0; r < 4; ++r) {
                const int m = m0 + wm + fm * 16 + quad * 4 + r;
                const int n = n0 + wn + fn * 16 + l15;
                const float v = acc[fm][fn][r] * scale;
                if (mode == 0) {
                    const int re = n < 1024 ? 0 : 64;
                    const int nn = n & 1023, h = nn >> 6, d = nn & 63;
                    ((ushort*)out0)[(size_t)m * KK + h * 128 + re + d] = f2b(v);
                } else if (mode == 1) {
                    const int nn = n & 1023, h = nn >> 6, dv = nn & 63;
                    const int bb = m >> 10, s = m & 1023;
                    const size_t row = ((size_t)((bb * HH + h) * 64 + dv)) * KK;
                    if (n < 1024) {   // real component vr
                        const ushort g = f2b(v);
                        ((ushort*)out0)[row + 2 * s]     = g;   // Vneg even = vr
                        ((ushort*)out1)[row + 2 * s + 1] = g;   // Vswap odd = vr
                    } else {          // imag component vi
                        ((ushort*)out0)[row + 2 * s + 1] = f2b(-v); // Vneg odd = -vi
                        ((ushort*)out1)[row + 2 * s]     = f2b(v);  // Vswap even = vi
                    }
                } else {
                    const int nn = n & 1023;
                    const size_t off = (size_t)m * 1024 + nn;
                    if (n < 1024) ((float*)out0)[off] = v + resr[off];
                    else          ((float*)out1)[off] = v + resi[off];
                }
            }
        }
    }
}

// merged QKV projection GEMM: blockIdx.z selects {Q, K, V}
__global__ __launch_bounds__(256) void bgemm_qkv(
    const ushort* __restrict__ Xq, const ushort* __restrict__ Xk,
    const ushort* __restrict__ Xv,
    const ushort* __restrict__ Bq, const ushort* __restrict__ Bk,
    const ushort* __restrict__ Bv,
    ushort* __restrict__ qpk, ushort* __restrict__ kpk,
    ushort* __restrict__ Vneg, ushort* __restrict__ Vswp)
{
    const int z = blockIdx.z;
    const ushort* A  = z == 0 ? Xq : z == 1 ? Xk : Xv;
    const ushort* Bm = z == 0 ? Bq : z == 1 ? Bk : Bv;
    void* o0 = z == 0 ? (void*)qpk : z == 1 ? (void*)kpk : (void*)Vneg;
    void* o1 = z == 2 ? (void*)Vswp : nullptr;
    const float sc = z == 0 ? 0.125f : 1.0f;
    const int mode = z == 2 ? 1 : 0;
    bgemm_body(A, Bm, o0, o1, nullptr, nullptr, sc, mode, blockIdx.x, blockIdx.y);
}

// fc GEMM: fp32 out + residual
__global__ __launch_bounds__(256) void bgemm_fc(
    const ushort* __restrict__ A, const ushort* __restrict__ Bm,
    float* __restrict__ fr, float* __restrict__ fi,
    const float* __restrict__ resr, const float* __restrict__ resi)
{
    bgemm_body(A, Bm, fr, fi, resr, resi, 1.0f, 2, blockIdx.x, blockIdx.y);
}

// ---------------------------------------------------------------------------
// Cooperative MFMA attention + exact streamed MagMinMaxNorm, TK=64/iteration.
//   o = (A - mn*P)/(mx - mn);  A = sum attn*v,  P = sum (attn/|attn|)*v
// Block = (32 q rows, h, b); wave (qt_w=w&1, kt_w=w>>1) computes the
// 16q x 32k QK^T subtile; interleaved-complex A/P staged in LDS (pk2 u32);
// AV: each wave owns 16 dv columns, contracts all 64 k per iteration.
// 2 barriers per 64 k. All 16 global frag loads issued at iteration top.
// Output: bf16 pack xo[m][2048] = [o_r (h*64+dv) | o_i].
// ---------------------------------------------------------------------------
#define APW 36   // u32 words per LDS row: 32 complex + 4 pad (144B, 16B-aligned)

__global__ __launch_bounds__(256) void attn_mfma(
    const ushort* __restrict__ qpk, const ushort* __restrict__ kpk,
    const ushort* __restrict__ vn, const ushort* __restrict__ vs,
    ushort* __restrict__ xo)
{
    __shared__ unsigned Alo[32 * APW], Ahi[32 * APW];
    __shared__ unsigned Plo[32 * APW], Phi[32 * APW];
    __shared__ unsigned mnb[32], mxb[32];

    const int tid  = threadIdx.x;
    const int wave = tid >> 6, lane = tid & 63;
    const int l15  = lane & 15, quad = lane >> 4;
    const int qt_w = wave & 1, kt_w = wave >> 1;
    const int qt = blockIdx.x, h = blockIdx.y, b = blockIdx.z;
    const size_t qrow0 = (size_t)b * SS + (size_t)qt * 32;

    if (tid < 32) { mnb[tid] = 0x7f800000u; mxb[tid] = 0u; }

    // Q fragments (A-operand), with pre-negated imag copies
    const ushort* qb = qpk + (qrow0 + qt_w * 16 + l15) * KK + h * 128 + quad * 8;
    shortx8 Aq0 = *(const shortx8*)(qb);
    shortx8 Aq1 = *(const shortx8*)(qb + 32);
    shortx8 Aq2 = *(const shortx8*)(qb + 64);
    shortx8 Aq3 = *(const shortx8*)(qb + 96);
    shortx8 Nq2 = negf(Aq2), Nq3 = negf(Aq3);

    // K rows for this wave's 32-k half of each 64-k iteration
    const ushort* kb = kpk + ((size_t)b * SS + kt_w * 32 + l15) * KK + h * 128 + quad * 8;
    // V pack rows: this wave's 16 dv columns
    const size_t vrow = ((size_t)((b * HH + h) * 64) + wave * 16 + l15) * KK + quad * 8;
    const ushort* vnb = vn + vrow;
    const ushort* vsb = vs + vrow;

    unsigned* Ab = kt_w ? Ahi : Alo;
    unsigned* Pb = kt_w ? Phi : Plo;

    floatx4 acc[2][4];   // [q-half][Ar,Ai,Pr,Pi]
    #pragma unroll
    for (int q2 = 0; q2 < 2; ++q2)
        #pragma unroll
        for (int j = 0; j < 4; ++j)
            acc[q2][j] = (floatx4){0.f, 0.f, 0.f, 0.f};
    float rmn[4] = {1e30f, 1e30f, 1e30f, 1e30f};
    float rmx[4] = {0.f, 0.f, 0.f, 0.f};

    for (int it = 0; it < 16; ++it) {
        // ---- issue ALL global fragment loads for this iteration up front ----
        const ushort* k0 = kb + (size_t)(it * 64) * KK;
        shortx8 Kf[2][4];
        #pragma unroll
        for (int kt2 = 0; kt2 < 2; ++kt2)
            #pragma unroll
            for (int f = 0; f < 4; ++f)
                Kf[kt2][f] = *(const shortx8*)(k0 + (size_t)(kt2 * 16) * KK + f * 32);
        shortx8 Vn_[4], Vs_[4];
        #pragma unroll
        for (int f = 0; f < 4; ++f) {
            Vn_[f] = *(const shortx8*)(vnb + it * 128 + f * 32);
            Vs_[f] = *(const shortx8*)(vsb + it * 128 + f * 32);
        }

        // ---- QK^T: 16q x 32k for this wave ----
        floatx4 cr[2], ci[2];
        #pragma unroll
        for (int kt2 = 0; kt2 < 2; ++kt2) {
            floatx4 r_ = (floatx4){0.f,0.f,0.f,0.f};
            floatx4 i_ = (floatx4){0.f,0.f,0.f,0.f};
            r_ = MFMA16(Aq0, Kf[kt2][0], r_); r_ = MFMA16(Aq1, Kf[kt2][1], r_);
            r_ = MFMA16(Nq2, Kf[kt2][2], r_); r_ = MFMA16(Nq3, Kf[kt2][3], r_);
            i_ = MFMA16(Aq2, Kf[kt2][0], i_); i_ = MFMA16(Aq3, Kf[kt2][1], i_);
            i_ = MFMA16(Aq0, Kf[kt2][2], i_); i_ = MFMA16(Aq1, Kf[kt2][3], i_);
            cr[kt2] = r_; ci[kt2] = i_;
        }

        __syncthreads();   // prior AV reads complete before buffer overwrite

        // ---- magnitude, phase, packed LDS writes ----
        #pragma unroll
        for (int kt2 = 0; kt2 < 2; ++kt2) {
            #pragma unroll
            for (int r = 0; r < 4; ++r) {
                const float ar = cr[kt2][r], ai = ci[kt2][r];
                const float s2 = fmaf(ar, ar, ai * ai);
                const float irm = s2 > 0.f ? rsqrtf(s2) : 0.f;
                const float mag = s2 * irm;
                rmn[r] = fminf(rmn[r], mag);
                rmx[r] = fmaxf(rmx[r], mag);
                const int w = (qt_w * 16 + quad * 4 + r) * APW + kt2 * 16 + l15;
                Ab[w] = pk2(ar, ai);
                Pb[w] = pk2(ar * irm, ai * irm);
            }
        }
        __syncthreads();   // writes visible to all waves

        // ---- AV: contract 64 k for both 16-q halves, this wave's 16 dv ----
        #pragma unroll
        for (int q2 = 0; q2 < 2; ++q2) {
            const int rw = (q2 * 16 + l15) * APW + quad * 4;
            shortx8 Af0 = *(const shortx8*)&Alo[rw];
            shortx8 Af1 = *(const shortx8*)&Alo[rw + 16];
            shortx8 Af2 = *(const shortx8*)&Ahi[rw];
            shortx8 Af3 = *(const shortx8*)&Ahi[rw + 16];
            shortx8 Pf0 = *(const shortx8*)&Plo[rw];
            shortx8 Pf1 = *(const shortx8*)&Plo[rw + 16];
            shortx8 Pf2 = *(const shortx8*)&Phi[rw];
            shortx8 Pf3 = *(const shortx8*)&Phi[rw + 16];
            acc[q2][0] = MFMA16(Af0, Vn_[0], acc[q2][0]);
            acc[q2][0] = MFMA16(Af1, Vn_[1], acc[q2][0]);
            acc[q2][0] = MFMA16(Af2, Vn_[2], acc[q2][0]);
            acc[q2][0] = MFMA16(Af3, Vn_[3], acc[q2][0]);
            acc[q2][1] = MFMA16(Af0, Vs_[0], acc[q2][1]);
            acc[q2][1] = MFMA16(Af1, Vs_[1], acc[q2][1]);
            acc[q2][1] = MFMA16(Af2, Vs_[2], acc[q2][1]);
            acc[q2][1] = MFMA16(Af3, Vs_[3], acc[q2][1]);
            acc[q2][2] = MFMA16(Pf0, Vn_[0], acc[q2][2]);
            acc[q2][2] = MFMA16(Pf1, Vn_[1], acc[q2][2]);
            acc[q2][2] = MFMA16(Pf2, Vn_[2], acc[q2][2]);
            acc[q2][2] = MFMA16(Pf3, Vn_[3], acc[q2][2]);
            acc[q2][3] = MFMA16(Pf0, Vs_[0], acc[q2][3]);
            acc[q2][3] = MFMA16(Pf1, Vs_[1], acc[q2][3]);
            acc[q2][3] = MFMA16(Pf2, Vs_[2], acc[q2][3]);
            acc[q2][3] = MFMA16(Pf3, Vs_[3], acc[q2][3]);
        }
    }

    // ---- per-row min/max: 16-lane shuffle, then cross-wave LDS atomics ----
    #pragma unroll
    for (int r = 0; r < 4; ++r) {
        float mn = rmn[r], mx = rmx[r];
        #pragma unroll
        for (int o = 1; o < 16; o <<= 1) {
            mn = fminf(mn, __shfl_xor(mn, o));
            mx = fmaxf(mx, __shfl_xor(mx, o));
        }
        if (l15 == 0) {
            const int q = qt_w * 16 + quad * 4 + r;
            atomicMin(&mnb[q], __float_as_uint(mn));   // mag >= 0: bits monotone
            atomicMax(&mxb[q], __float_as_uint(mx));
        }
    }
    __syncthreads();

    // ---- epilogue: o = (A - mn*P)/(mx - mn) -> bf16 pack ----
    #pragma unroll
    for (int q2 = 0; q2 < 2; ++q2) {
        #pragma unroll
        for (int r = 0; r < 4; ++r) {
            const int q = q2 * 16 + quad * 4 + r;
            const float mn = __uint_as_float(mnb[q]);
            const float mx = __uint_as_float(mxb[q]);
            const float d = mx - mn;
            const float invd = d > 0.f ? 1.f / d : 0.f;
            const float vr_ = (acc[q2][0][r] - mn * acc[q2][2][r]) * invd;
            const float vi_ = (acc[q2][1][r] - mn * acc[q2][3][r]) * invd;
            const size_t row = (qrow0 + q) * KK + h * 64 + wave * 16 + l15;
            xo[row]        = f2b(vr_);
            xo[row + 1024] = f2b(vi_);
        }
    }
}

// ---------------------------------------------------------------------------
// Complex covariance-whitening layernorm, one wave per (b,s) row.
// ---------------------------------------------------------------------------
__global__ __launch_bounds__(256) void ln_kernel(
    const float* __restrict__ xr, const float* __restrict__ xi,
    const float* __restrict__ g_rr, const float* __restrict__ g_ri,
    const float* __restrict__ g_ii,
    const float* __restrict__ b_r, const float* __restrict__ b_i,
    float* __restrict__ out)
{
    const int lane = threadIdx.x & 63;
    const int wave = threadIdx.x >> 6;
    const int row  = blockIdx.x * 4 + wave;
    const float* pr = xr + (size_t)row * DD;
    const float* pi = xi + (size_t)row * DD;

    float r[16], im[16];
    float sr = 0.f, si = 0.f;
    #pragma unroll
    for (int j = 0; j < 16; ++j) {
        r[j]  = pr[lane + 64*j];
        im[j] = pi[lane + 64*j];
        sr += r[j]; si += im[j];
    }
    #pragma unroll
    for (int o = 32; o; o >>= 1) { sr += __shfl_xor(sr, o); si += __shfl_xor(si, o); }
    const float mr = sr * (1.f / DD), mi = si * (1.f / DD);

    float srr = 0.f, sii = 0.f, sri = 0.f;
    #pragma unroll
    for (int j = 0; j < 16; ++j) {
        const float a = r[j] - mr, c = im[j] - mi;
        srr = fmaf(a, a, srr); sii = fmaf(c, c, sii); sri = fmaf(a, c, sri);
    }
    #pragma unroll
    for (int o = 32; o; o >>= 1) {
        srr += __shfl_xor(srr, o); sii += __shfl_xor(sii, o); sri += __shfl_xor(sri, o);
    }
    const float Vrr = srr * (1.f / DD) + EPS_LN;
    const float Vii = sii * (1.f / DD) + EPS_LN;
    const float Vri = sri * (1.f / DD);
    const float s  = sqrtf(Vrr * Vii - Vri * Vri);
    const float t  = sqrtf(Vrr + Vii + 2.f * s);
    const float inv = 1.f / (s * t);
    const float Wrr = (Vii + s) * inv;
    const float Wii = (Vrr + s) * inv;
    const float Wri = -Vri * inv;

    #pragma unroll
    for (int j = 0; j < 16; ++j) {
        const int d = lane + 64*j;
        const float a = r[j] - mr, c = im[j] - mi;
        const float or_ = Wrr * a + Wri * c;
        const float oi_ = Wri * a + Wii * c;
        out[(size_t)row * DD + d] = g_rr[d]*or_ + g_ri[d]*oi_ + b_r[d];
        out[(size_t)(M_ROWS) * DD + (size_t)row * DD + d] = g_ri[d]*or_ + g_ii[d]*oi_ + b_i[d];
    }
}

// ---------------------------------------------------------------------------
extern "C" void kernel_launch(void* const* d_in, const int* in_sizes, int n_in,
                              void* d_out, int out_size, void* d_ws, size_t ws_size,
                              hipStream_t stream) {
    const float* q_r  = (const float*)d_in[0];
    const float* q_i  = (const float*)d_in[1];
    const float* k_r  = (const float*)d_in[2];
    const float* k_i  = (const float*)d_in[3];
    const float* v_r  = (const float*)d_in[4];
    const float* v_i  = (const float*)d_in[5];
    const float* wq_r = (const float*)d_in[6];
    const float* wq_i = (const float*)d_in[7];
    const float* wk_r = (const float*)d_in[8];
    const float* wk_i = (const float*)d_in[9];
    const float* wv_r = (const float*)d_in[10];
    const float* wv_i = (const float*)d_in[11];
    const float* fc_r = (const float*)d_in[12];
    const float* fc_i = (const float*)d_in[13];
    const float* g_rr = (const float*)d_in[14];
    const float* g_ri = (const float*)d_in[15];
    const float* g_ii = (const float*)d_in[16];
    const float* b_r  = (const float*)d_in[17];
    const float* b_i  = (const float*)d_in[18];
    float* out = (float*)d_out;

    // Workspace: 7 units of 16 MiB = 112 MiB.
    float* ws = (float*)d_ws;
    const size_t NE = (size_t)M_ROWS * 1024;        // 4M floats = 16 MiB
    ushort* Xq   = (ushort*)(ws + 0 * NE);          // u0; later Vneg
    ushort* Xk   = (ushort*)(ws + 1 * NE);          // u1; later Vswap
    ushort* Xv   = (ushort*)(ws + 2 * NE);          // u2; later xo
    ushort* qpk  = (ushort*)(ws + 3 * NE);          // u3; later fr
    ushort* kpk  = (ushort*)(ws + 4 * NE);          // u4; later fi
    ushort* Bq   = (ushort*)(ws + 5 * NE);          // u5 lo
    ushort* Bk   = Bq + (size_t)KK * KK;            // u5 hi
    ushort* Bv   = (ushort*)(ws + 6 * NE);          // u6 lo
    ushort* Bf   = Bv + (size_t)KK * KK;            // u6 hi
    ushort* Vneg = (ushort*)(ws + 0 * NE);          // aliases dead Xq
    ushort* Vswp = (ushort*)(ws + 1 * NE);          // aliases dead Xk
    ushort* xo   = (ushort*)(ws + 2 * NE);          // aliases dead Xv
    float*  fr   = ws + 3 * NE;                     // aliases dead qpk
    float*  fi   = ws + 4 * NE;                     // aliases dead kpk

    // bf16 operand packing
    pack_x<<<dim3(4096, 3), 256, 0, stream>>>(q_r, q_i, k_r, k_i, v_r, v_i, Xq, Xk, Xv);
    pack_w<<<dim3(1024, 4), 256, 0, stream>>>(wq_r, wq_i, wk_r, wk_i, wv_r, wv_i,
                                              fc_r, fc_i, Bq, Bk, Bv, Bf);

    // merged QKV projections (q gets 1/sqrt(DK) folded in): 1536 blocks
    bgemm_qkv<<<dim3(KK / BN, M_ROWS / BM, 3), 256, 0, stream>>>(
        Xq, Xk, Xv, Bq, Bk, Bv, qpk, kpk, Vneg, Vswp);

    // cooperative MFMA attention + MagMinMaxNorm -> bf16 [4096][2048] pack
    attn_mfma<<<dim3(SS / 32, HH, BB), 256, 0, stream>>>(qpk, kpk, Vneg, Vswp, xo);

    // output projection + residual (bf16 MFMA, fp32 out)
    bgemm_fc<<<dim3(KK / BN, M_ROWS / BM), 256, 0, stream>>>(xo, Bf, fr, fi, q_r, q_i);

    // complex layernorm -> d_out [2,B,S,D]
    ln_kernel<<<M_ROWS / 4, 256, 0, stream>>>(fr, fi, g_rr, g_ri, g_ii, b_r, b_i, out);
}